// Round 1
// baseline (245.954 us; speedup 1.0000x reference)
//
#include <hip/hip_runtime.h>
#include <math.h>

#define S 256
#define V 200
#define NF 5
#define NROT 16
#define G 80
#define FG 400   // NF*G
#define EPSF 1e-5f
#define T2PI 6.28318530717958647692f
#define LOG2E 1.44269504088896340736f
#define OUT_DESC 20480        // 256*80
#define OUT_LOSS 20480
#define OUT_SCORE 20481

// ---------------- K1: gd[f][r][s][g] = sum_v(ga*feat) / (sum_v ga + eps) ----
__global__ __launch_bounds__(256) void k1_gd(
    const float* __restrict__ feat,   // (S,V,NF)
    const float* __restrict__ rho,    // (S,V)
    const float* __restrict__ theta,  // (S,V)
    const float* __restrict__ mask,   // (S,V)
    const float* __restrict__ mu_rho, const float* __restrict__ sig_rho,
    const float* __restrict__ mu_th,  const float* __restrict__ sig_th,
    float* __restrict__ gd)           // (NF,NROT,S,G)
{
    const int s   = blockIdx.x;
    const int r   = blockIdx.y;
    const int tid = threadIdx.x;

    __shared__ float4 pk[V];       // {rho, theta_rot, mask, pad}
    __shared__ float  ft[NF * V];  // feat transposed: [f][v]

    // rot step computed in double then cast — matches jnp f32 arithmetic
    const float rot = (float)r * (float)(6.283185307179586 / 16.0);

    for (int v = tid; v < V; v += 256) {
        float t = theta[s * V + v] + rot;
        if (t >= T2PI) t -= T2PI;          // theta in [0,2pi), rot in [0,2pi)
        pk[v] = make_float4(rho[s * V + v], t, mask[s * V + v], 0.f);
    }
    for (int i = tid; i < NF * V; i += 256) {
        int v = i / NF, f = i % NF;
        ft[f * V + v] = feat[(s * V + v) * NF + f];
    }
    __syncthreads();

    for (int fg = tid; fg < FG; fg += 256) {
        const int f = fg / G;            // mu arrays are (NF,G) → flat index fg
        const float mr = mu_rho[fg];
        const float sr = sig_rho[fg];
        const float mt = mu_th[fg];
        const float st = sig_th[fg];
        const float ninr = -LOG2E / (sr * sr + EPSF);
        const float nint = -LOG2E / (st * st + EPSF);
        const float* __restrict__ fp = &ft[f * V];

        float num = 0.f, den = 0.f;
        #pragma unroll 4
        for (int v = 0; v < V; ++v) {
            float4 p = pk[v];
            float dr = p.x - mr;
            float dt = p.y - mt;
            float e  = fmaf(dt * dt, nint, dr * dr * ninr);
            float w  = exp2f(e) * p.z;
            num = fmaf(w, fp[v], num);
            den += w;
        }
        gd[((f * NROT + r) * S + s) * G + (fg % G)] = num / (den + EPSF);
    }
}

// ---------------- K2: cf = gd @ W_conv + b_conv[f]; desc = relu(max_r cf) ----
__global__ __launch_bounds__(320) void k2_conv(
    const float* __restrict__ gd,    // (NF,NROT,S,G)
    const float* __restrict__ Wc,    // (G,G)
    const float* __restrict__ bc,    // (NF,G)
    float* __restrict__ desc)        // (S, FG)
{
    const int s = blockIdx.x, f = blockIdx.y;
    const int tid  = threadIdx.x;
    const int gout = tid % G;        // 0..79
    const int rq   = tid / G;        // 0..3

    __shared__ float gds[NROT * G];
    __shared__ float red[320];

    for (int i = tid; i < NROT * G; i += 320) {
        int r = i / G, g = i % G;
        gds[i] = gd[((f * NROT + r) * S + s) * G + g];
    }
    __syncthreads();

    const float bb = bc[f * G + gout];
    float m = -INFINITY;
    for (int rr = 0; rr < 4; ++rr) {
        const float* __restrict__ row = &gds[(rq * 4 + rr) * G];
        float c = bb;
        #pragma unroll 8
        for (int gi = 0; gi < G; ++gi)
            c = fmaf(row[gi], Wc[gi * G + gout], c);
        m = fmaxf(m, c);
    }
    red[tid] = m;
    __syncthreads();
    if (tid < G) {
        float mm = fmaxf(fmaxf(red[tid], red[tid + 80]),
                         fmaxf(red[tid + 160], red[tid + 240]));
        desc[s * FG + f * G + tid] = fmaxf(mm, 0.f);
    }
}

// ---------------- K3: global_desc = desc @ fcc_w + fcc_b --------------------
__global__ __launch_bounds__(128) void k3_fcc(
    const float* __restrict__ desc,  // (S,FG)
    const float* __restrict__ fw,    // (FG,G)
    const float* __restrict__ fb,    // (G)
    float* __restrict__ out)         // d_out: first S*G floats
{
    const int s = blockIdx.x, tid = threadIdx.x;
    __shared__ float row[FG];
    for (int i = tid; i < FG; i += 128) row[i] = desc[s * FG + i];
    __syncthreads();
    if (tid < G) {
        float acc = fb[tid];
        #pragma unroll 8
        for (int k = 0; k < FG; ++k)
            acc = fmaf(row[k], fw[k * G + tid], acc);
        out[s * G + tid] = acc;
    }
}

// ---------------- K4: score + data_loss -------------------------------------
__global__ __launch_bounds__(128) void k4_loss(
    const float* __restrict__ gdesc,  // d_out[0 .. S*G)
    float* __restrict__ out)
{
    const int tid  = threadIdx.x;     // 0..127
    const int wave = tid >> 6;        // 0: pos pairs, 1: neg pairs
    const int lane = tid & 63;

    const float* a;
    const float* b;
    if (wave == 0) { a = gdesc + (64  + lane) * G; b = gdesc + lane        * G; }
    else           { a = gdesc + (128 + lane) * G; b = gdesc + (192 + lane) * G; }

    float d = 0.f;
    #pragma unroll 8
    for (int g = 0; g < G; ++g) { float df = a[g] - b[g]; d = fmaf(df, df, d); }
    out[OUT_SCORE + tid] = d;

    float rv = (wave == 0) ? fmaxf(d - 0.0f, 0.f) : fmaxf(10.0f - d, 0.f);

    float sum = rv;
    for (int off = 32; off > 0; off >>= 1) sum += __shfl_xor(sum, off);
    float mean = sum * (1.f / 64.f);
    float dv = rv - mean;
    float sq = dv * dv;
    for (int off = 32; off > 0; off >>= 1) sq += __shfl_xor(sq, off);
    float stdv = sqrtf(sq * (1.f / 63.f));   // ddof=1

    __shared__ float part[2];
    if (lane == 0) part[wave] = mean + stdv;
    __syncthreads();
    if (tid == 0) out[OUT_LOSS] = part[0] + part[1];
}

extern "C" void kernel_launch(void* const* d_in, const int* in_sizes, int n_in,
                              void* d_out, int out_size, void* d_ws, size_t ws_size,
                              hipStream_t stream) {
    const float* feat    = (const float*)d_in[0];
    const float* rho     = (const float*)d_in[1];
    const float* theta   = (const float*)d_in[2];
    const float* mask    = (const float*)d_in[3];
    const float* mu_rho  = (const float*)d_in[4];
    const float* sig_rho = (const float*)d_in[5];
    const float* mu_th   = (const float*)d_in[6];
    const float* sig_th  = (const float*)d_in[7];
    const float* Wc      = (const float*)d_in[8];
    const float* bc      = (const float*)d_in[9];
    const float* fw      = (const float*)d_in[10];
    const float* fb      = (const float*)d_in[11];

    float* out  = (float*)d_out;
    float* gd   = (float*)d_ws;                 // NF*NROT*S*G = 1,638,400 floats
    float* desc = gd + NF * NROT * S * G;       // S*FG       =   102,400 floats

    k1_gd  <<<dim3(S, NROT), 256, 0, stream>>>(feat, rho, theta, mask,
                                               mu_rho, sig_rho, mu_th, sig_th, gd);
    k2_conv<<<dim3(S, NF),   320, 0, stream>>>(gd, Wc, bc, desc);
    k3_fcc <<<S,             128, 0, stream>>>(desc, fw, fb, out);
    k4_loss<<<1,             128, 0, stream>>>(out, out);
}

// Round 2
// 164.201 us; speedup vs baseline: 1.4979x; 1.4979x over previous
//
#include <hip/hip_runtime.h>
#include <math.h>

#define S 256
#define V 200
#define NF 5
#define NROT 16
#define G 80
#define FG 400
#define EPSF 1e-5f
#define T2PI 6.28318530717958647692f
#define NLOG2E (-1.44269504088896340736f)
#define KP 224          // V padded to 7 * 32 for MFMA K-steps
#define VP 228          // Ft row stride (228%32=4 -> bank-spread, 16B aligned)
#define OUT_LOSS 20480
#define OUT_SCORE 20481

typedef __attribute__((ext_vector_type(8))) short bfrag8;   // 8 bf16 (4 VGPRs)
typedef __attribute__((ext_vector_type(4))) float facc4;    // 4 f32 acc

static __device__ __forceinline__ short bft(float x) {
    return (short)(__float_as_uint(x) >> 16);   // f32 -> bf16 truncate
}

// ---------------- K1: separable gaussians + MFMA contraction over v ---------
// Per (s,r) block (1 wave): out[it, ir*6+fh] = sum_v T[v,it] * R[v,ir]*mask*F[v,fh]
// A[16=it][K=v] = T ; B[K=v][30 cols=(ir,fh)] ; fh==5 column accumulates den.
__global__ __launch_bounds__(64) void k1_gd(
    const float* __restrict__ feat,   // (S,V,NF)
    const float* __restrict__ rho,    // (S,V)
    const float* __restrict__ theta,  // (S,V)
    const float* __restrict__ mask,   // (S,V)
    const float* __restrict__ mu_rho, const float* __restrict__ sig_rho,
    const float* __restrict__ mu_th,  const float* __restrict__ sig_th,
    float* __restrict__ gd)           // (NF,NROT,S,G)
{
    const int s    = blockIdx.x;
    const int r    = blockIdx.y;
    const int lane = threadIdx.x;
    const int n    = lane & 15;
    const int quad = lane >> 4;

    __shared__ float thr[KP];
    __shared__ float rhm[KP];
    __shared__ float FtL[6 * VP];     // [fh][v]: feat*mask rows 0..4, mask row 5
    __shared__ float cT[32 * 16];     // [col][row=it]

    const float rot = (float)r * (float)(6.283185307179586 / 16.0);

    for (int v = lane; v < KP; v += 64) {
        float th = 0.f, rh = 0.f, mk = 0.f;
        float f0 = 0.f, f1 = 0.f, f2 = 0.f, f3 = 0.f, f4 = 0.f;
        if (v < V) {
            th = theta[s * V + v] + rot;
            if (th >= T2PI) th -= T2PI;
            rh = rho[s * V + v];
            mk = mask[s * V + v];
            const float* fp = &feat[(s * V + v) * NF];
            f0 = fp[0] * mk; f1 = fp[1] * mk; f2 = fp[2] * mk;
            f3 = fp[3] * mk; f4 = fp[4] * mk;
        }
        thr[v] = th; rhm[v] = rh;
        FtL[0 * VP + v] = f0; FtL[1 * VP + v] = f1; FtL[2 * VP + v] = f2;
        FtL[3 * VP + v] = f3; FtL[4 * VP + v] = f4; FtL[5 * VP + v] = mk;
    }

    // per-lane constants: A-side it = n; B-side cols n (tile0) and 16+n (tile1)
    const float mu_t = mu_th[n];                 // g = 0*16+it row (ir=0)
    const float stn  = sig_th[n];
    const float ct   = NLOG2E / (stn * stn + EPSF);

    const int   c0 = n;        const int ir0 = c0 / 6, fh0 = c0 % 6;
    const int   c1 = 16 + n;   const bool vl1 = (c1 < 30);
    const int   ir1 = c1 / 6;  const int  fh1 = (c1 % 6);
    const float mu_r0 = mu_rho[ir0 * 16];        // g = ir*16 (it=0)
    const float sr0   = sig_rho[ir0 * 16];
    const float cr0   = NLOG2E / (sr0 * sr0 + EPSF);
    const float mu_r1 = mu_rho[ir1 * 16];        // ir1<=5 -> idx<=80, in-bounds
    const float sr1   = sig_rho[ir1 * 16];
    const float cr1   = NLOG2E / (sr1 * sr1 + EPSF);
    const int   fh1s  = vl1 ? fh1 : 0;

    __syncthreads();

    facc4 acc0 = {0.f, 0.f, 0.f, 0.f};
    facc4 acc1 = {0.f, 0.f, 0.f, 0.f};

    for (int kk = 0; kk < KP / 32; ++kk) {
        const int vb = kk * 32 + quad * 8;
        const float4 t0 = *(const float4*)&thr[vb];
        const float4 t1 = *(const float4*)&thr[vb + 4];
        const float4 p0 = *(const float4*)&rhm[vb];
        const float4 p1 = *(const float4*)&rhm[vb + 4];
        const float4 g0 = *(const float4*)&FtL[fh0 * VP + vb];
        const float4 g1 = *(const float4*)&FtL[fh0 * VP + vb + 4];
        const float4 h0 = *(const float4*)&FtL[fh1s * VP + vb];
        const float4 h1 = *(const float4*)&FtL[fh1s * VP + vb + 4];

        const float tv[8] = {t0.x, t0.y, t0.z, t0.w, t1.x, t1.y, t1.z, t1.w};
        const float pv[8] = {p0.x, p0.y, p0.z, p0.w, p1.x, p1.y, p1.z, p1.w};
        const float gv[8] = {g0.x, g0.y, g0.z, g0.w, g1.x, g1.y, g1.z, g1.w};
        const float hv[8] = {h0.x, h0.y, h0.z, h0.w, h1.x, h1.y, h1.z, h1.w};

        bfrag8 af, b0, b1;
        #pragma unroll
        for (int j = 0; j < 8; ++j) {
            float dt = tv[j] - mu_t;
            af[j] = bft(__builtin_amdgcn_exp2f(ct * dt * dt));
            float dra = pv[j] - mu_r0;
            b0[j] = bft(__builtin_amdgcn_exp2f(cr0 * dra * dra) * gv[j]);
            float drb = pv[j] - mu_r1;
            float w1  = vl1 ? __builtin_amdgcn_exp2f(cr1 * drb * drb) * hv[j] : 0.f;
            b1[j] = bft(w1);
        }
        acc0 = __builtin_amdgcn_mfma_f32_16x16x32_bf16(af, b0, acc0, 0, 0, 0);
        acc1 = __builtin_amdgcn_mfma_f32_16x16x32_bf16(af, b1, acc1, 0, 0, 0);
    }

    // C/D layout: col = lane&15, row = quad*4 + reg  -> store transposed [col][row]
    #pragma unroll
    for (int i = 0; i < 4; ++i) {
        cT[c0 * 16 + quad * 4 + i] = acc0[i];
        cT[c1 * 16 + quad * 4 + i] = acc1[i];
    }
    __syncthreads();

    for (int i = lane; i < 400; i += 64) {
        int it  = i & 15;
        int c25 = i >> 4;               // 0..24
        int ir  = c25 / 5, f = c25 % 5;
        float num = cT[(ir * 6 + f) * 16 + it];
        float den = cT[(ir * 6 + 5) * 16 + it];
        gd[((f * NROT + r) * S + s) * G + ir * 16 + it] = num / (den + EPSF);
    }
}

// ---------------- K2: cf = gd @ W_conv + b_conv[f]; desc = relu(max_r cf) ----
// block = s; wave w owns r = w*4+rr (wave-uniform -> gd rows via s_load);
// W_conv column register-resident per thread.
__global__ __launch_bounds__(256) void k2_conv(
    const float* __restrict__ gd,    // (NF,NROT,S,G)
    const float* __restrict__ Wc,    // (G,G)
    const float* __restrict__ bc,    // (NF,G)
    float* __restrict__ desc)        // (S, FG)
{
    const int s    = blockIdx.x;
    const int tid  = threadIdx.x;
    const int w    = __builtin_amdgcn_readfirstlane(tid >> 6);
    const int lane = tid & 63;

    __shared__ float red[4 * G];

    for (int go2 = 0; go2 < 2; ++go2) {
        const int gout = go2 * 64 + lane;
        const bool act = gout < G;
        float wcol[G];
        #pragma unroll
        for (int gi = 0; gi < G; ++gi)
            wcol[gi] = act ? Wc[gi * G + gout] : 0.f;

        for (int f = 0; f < NF; ++f) {
            float mx = -INFINITY;
            for (int rr = 0; rr < 4; ++rr) {
                const int rrow = w * 4 + rr;
                const float* __restrict__ grow = &gd[((f * NROT + rrow) * S + s) * G];
                float c = 0.f;
                #pragma unroll
                for (int gi = 0; gi < G; ++gi)
                    c = fmaf(grow[gi], wcol[gi], c);   // grow[gi] wave-uniform -> s_load
                mx = fmaxf(mx, c);
            }
            if (act) red[w * G + gout] = mx;
            __syncthreads();
            if (tid < (go2 ? 16 : 64)) {
                int go = go2 * 64 + tid;
                float m = fmaxf(fmaxf(red[0 * G + go], red[1 * G + go]),
                                fmaxf(red[2 * G + go], red[3 * G + go]));
                desc[s * FG + f * G + go] = fmaxf(m + bc[f * G + go], 0.f);
            }
            __syncthreads();
        }
    }
}

// ---------------- K3: global_desc = desc @ fcc_w + fcc_b --------------------
__global__ __launch_bounds__(128) void k3_fcc(
    const float* __restrict__ desc,  // (S,FG)
    const float* __restrict__ fw,    // (FG,G)
    const float* __restrict__ fb,    // (G)
    float* __restrict__ out)         // d_out: first S*G floats
{
    const int s = blockIdx.x, tid = threadIdx.x;
    if (tid < G) {
        float acc = fb[tid];
        const float* __restrict__ drow = &desc[s * FG];   // uniform -> s_load
        #pragma unroll 8
        for (int k = 0; k < FG; ++k)
            acc = fmaf(drow[k], fw[k * G + tid], acc);
        out[s * G + tid] = acc;
    }
}

// ---------------- K4: score + data_loss -------------------------------------
__global__ __launch_bounds__(128) void k4_loss(
    const float* __restrict__ gdesc,  // d_out[0 .. S*G)
    float* __restrict__ out)
{
    const int tid  = threadIdx.x;
    const int wave = tid >> 6;
    const int lane = tid & 63;

    const float* a;
    const float* b;
    if (wave == 0) { a = gdesc + (64  + lane) * G; b = gdesc + lane         * G; }
    else           { a = gdesc + (128 + lane) * G; b = gdesc + (192 + lane) * G; }

    float d = 0.f;
    #pragma unroll 8
    for (int g = 0; g < G; ++g) { float df = a[g] - b[g]; d = fmaf(df, df, d); }
    out[OUT_SCORE + tid] = d;

    float rv = (wave == 0) ? fmaxf(d - 0.0f, 0.f) : fmaxf(10.0f - d, 0.f);

    float sum = rv;
    for (int off = 32; off > 0; off >>= 1) sum += __shfl_xor(sum, off);
    float mean = sum * (1.f / 64.f);
    float dv = rv - mean;
    float sq = dv * dv;
    for (int off = 32; off > 0; off >>= 1) sq += __shfl_xor(sq, off);
    float stdv = sqrtf(sq * (1.f / 63.f));   // ddof=1

    __shared__ float part[2];
    if (lane == 0) part[wave] = mean + stdv;
    __syncthreads();
    if (tid == 0) out[OUT_LOSS] = part[0] + part[1];
}

extern "C" void kernel_launch(void* const* d_in, const int* in_sizes, int n_in,
                              void* d_out, int out_size, void* d_ws, size_t ws_size,
                              hipStream_t stream) {
    const float* feat    = (const float*)d_in[0];
    const float* rho     = (const float*)d_in[1];
    const float* theta   = (const float*)d_in[2];
    const float* mask    = (const float*)d_in[3];
    const float* mu_rho  = (const float*)d_in[4];
    const float* sig_rho = (const float*)d_in[5];
    const float* mu_th   = (const float*)d_in[6];
    const float* sig_th  = (const float*)d_in[7];
    const float* Wc      = (const float*)d_in[8];
    const float* bc      = (const float*)d_in[9];
    const float* fw      = (const float*)d_in[10];
    const float* fb      = (const float*)d_in[11];

    float* out  = (float*)d_out;
    float* gd   = (float*)d_ws;                 // NF*NROT*S*G floats
    float* desc = gd + NF * NROT * S * G;       // S*FG floats

    k1_gd  <<<dim3(S, NROT), 64, 0, stream>>>(feat, rho, theta, mask,
                                              mu_rho, sig_rho, mu_th, sig_th, gd);
    k2_conv<<<S,             256, 0, stream>>>(gd, Wc, bc, desc);
    k3_fcc <<<S,             128, 0, stream>>>(desc, fw, fb, out);
    k4_loss<<<1,             128, 0, stream>>>(out, out);
}

// Round 3
// 106.551 us; speedup vs baseline: 2.3083x; 1.5411x over previous
//
#include <hip/hip_runtime.h>
#include <math.h>

#define S 256
#define V 200
#define NF 5
#define NROT 16
#define G 80
#define FG 400
#define EPSF 1e-5f
#define T2PI 6.28318530717958647692f
#define NLOG2E (-1.44269504088896340736f)
#define KP 224          // V padded to 7 * 32 for MFMA K-steps
#define VP 228          // Ft row stride
#define AK 96           // K=80 padded to 96 (3 MFMA k-steps) for k2
#define OUT_LOSS 20480
#define OUT_SCORE 20481

typedef __attribute__((ext_vector_type(8))) short bfrag8;   // 8 bf16 (4 VGPRs)
typedef __attribute__((ext_vector_type(4))) float facc4;    // 4 f32 acc

static __device__ __forceinline__ short bft(float x) {
    return (short)(__float_as_uint(x) >> 16);   // f32 -> bf16 truncate
}
static __device__ __forceinline__ short bfr(float x) {      // round-to-nearest-even
    unsigned u = __float_as_uint(x);
    u += 0x7FFFu + ((u >> 16) & 1u);
    return (short)(u >> 16);
}

// ---------------- K1: separable gaussians + MFMA contraction over v ---------
__global__ __launch_bounds__(64) void k1_gd(
    const float* __restrict__ feat,   // (S,V,NF)
    const float* __restrict__ rho,    // (S,V)
    const float* __restrict__ theta,  // (S,V)
    const float* __restrict__ mask,   // (S,V)
    const float* __restrict__ mu_rho, const float* __restrict__ sig_rho,
    const float* __restrict__ mu_th,  const float* __restrict__ sig_th,
    float* __restrict__ gd)           // (NF,NROT,S,G)
{
    const int s    = blockIdx.x;
    const int r    = blockIdx.y;
    const int lane = threadIdx.x;
    const int n    = lane & 15;
    const int quad = lane >> 4;

    __shared__ float thr[KP];
    __shared__ float rhm[KP];
    __shared__ float FtL[6 * VP];     // [fh][v]: feat*mask rows 0..4, mask row 5
    __shared__ float cT[32 * 16];     // [col][row=it]

    const float rot = (float)r * (float)(6.283185307179586 / 16.0);

    for (int v = lane; v < KP; v += 64) {
        float th = 0.f, rh = 0.f, mk = 0.f;
        float f0 = 0.f, f1 = 0.f, f2 = 0.f, f3 = 0.f, f4 = 0.f;
        if (v < V) {
            th = theta[s * V + v] + rot;
            if (th >= T2PI) th -= T2PI;
            rh = rho[s * V + v];
            mk = mask[s * V + v];
            const float* fp = &feat[(s * V + v) * NF];
            f0 = fp[0] * mk; f1 = fp[1] * mk; f2 = fp[2] * mk;
            f3 = fp[3] * mk; f4 = fp[4] * mk;
        }
        thr[v] = th; rhm[v] = rh;
        FtL[0 * VP + v] = f0; FtL[1 * VP + v] = f1; FtL[2 * VP + v] = f2;
        FtL[3 * VP + v] = f3; FtL[4 * VP + v] = f4; FtL[5 * VP + v] = mk;
    }

    const float mu_t = mu_th[n];
    const float stn  = sig_th[n];
    const float ct   = NLOG2E / (stn * stn + EPSF);

    const int   c0 = n;        const int ir0 = c0 / 6, fh0 = c0 % 6;
    const int   c1 = 16 + n;   const bool vl1 = (c1 < 30);
    const int   ir1 = c1 / 6;  const int  fh1 = (c1 % 6);
    const float mu_r0 = mu_rho[ir0 * 16];
    const float sr0   = sig_rho[ir0 * 16];
    const float cr0   = NLOG2E / (sr0 * sr0 + EPSF);
    const float mu_r1 = mu_rho[ir1 * 16];
    const float sr1   = sig_rho[ir1 * 16];
    const float cr1   = NLOG2E / (sr1 * sr1 + EPSF);
    const int   fh1s  = vl1 ? fh1 : 0;

    __syncthreads();

    facc4 acc0 = {0.f, 0.f, 0.f, 0.f};
    facc4 acc1 = {0.f, 0.f, 0.f, 0.f};

    for (int kk = 0; kk < KP / 32; ++kk) {
        const int vb = kk * 32 + quad * 8;
        const float4 t0 = *(const float4*)&thr[vb];
        const float4 t1 = *(const float4*)&thr[vb + 4];
        const float4 p0 = *(const float4*)&rhm[vb];
        const float4 p1 = *(const float4*)&rhm[vb + 4];
        const float4 g0 = *(const float4*)&FtL[fh0 * VP + vb];
        const float4 g1 = *(const float4*)&FtL[fh0 * VP + vb + 4];
        const float4 h0 = *(const float4*)&FtL[fh1s * VP + vb];
        const float4 h1 = *(const float4*)&FtL[fh1s * VP + vb + 4];

        const float tv[8] = {t0.x, t0.y, t0.z, t0.w, t1.x, t1.y, t1.z, t1.w};
        const float pv[8] = {p0.x, p0.y, p0.z, p0.w, p1.x, p1.y, p1.z, p1.w};
        const float gv[8] = {g0.x, g0.y, g0.z, g0.w, g1.x, g1.y, g1.z, g1.w};
        const float hv[8] = {h0.x, h0.y, h0.z, h0.w, h1.x, h1.y, h1.z, h1.w};

        bfrag8 af, b0, b1;
        #pragma unroll
        for (int j = 0; j < 8; ++j) {
            float dt = tv[j] - mu_t;
            af[j] = bft(__builtin_amdgcn_exp2f(ct * dt * dt));
            float dra = pv[j] - mu_r0;
            b0[j] = bft(__builtin_amdgcn_exp2f(cr0 * dra * dra) * gv[j]);
            float drb = pv[j] - mu_r1;
            float w1  = vl1 ? __builtin_amdgcn_exp2f(cr1 * drb * drb) * hv[j] : 0.f;
            b1[j] = bft(w1);
        }
        acc0 = __builtin_amdgcn_mfma_f32_16x16x32_bf16(af, b0, acc0, 0, 0, 0);
        acc1 = __builtin_amdgcn_mfma_f32_16x16x32_bf16(af, b1, acc1, 0, 0, 0);
    }

    #pragma unroll
    for (int i = 0; i < 4; ++i) {
        cT[c0 * 16 + quad * 4 + i] = acc0[i];
        cT[c1 * 16 + quad * 4 + i] = acc1[i];
    }
    __syncthreads();

    for (int i = lane; i < 400; i += 64) {
        int it  = i & 15;
        int c25 = i >> 4;
        int ir  = c25 / 5, f = c25 % 5;
        float num = cT[(ir * 6 + f) * 16 + it];
        float den = cT[(ir * 6 + 5) * 16 + it];
        gd[((f * NROT + r) * S + s) * G + ir * 16 + it] = num / (den + EPSF);
    }
}

// ---------------- K2: conv + max_r + relu + fcc, fused, MFMA ----------------
// One block per s, 320 threads = 5 waves; wave w = feature f.
// A[80 rows=(f*16+r)][K=g]=gd ; B[K=g][80 cols]=W_conv ; 16x16x32 bf16 MFMA.
__global__ __launch_bounds__(320) void k2_conv_fcc(
    const float* __restrict__ gd,    // (NF,NROT,S,G) = rows (f*16+r) stride S*G
    const float* __restrict__ Wc,    // (G,G)
    const float* __restrict__ bc,    // (NF,G)
    const float* __restrict__ fw,    // (FG,G)
    const float* __restrict__ fb,    // (G)
    float* __restrict__ out)         // d_out: first S*G floats
{
    const int s    = blockIdx.x;
    const int tid  = threadIdx.x;
    const int w    = tid >> 6;       // wave id = f
    const int lane = tid & 63;
    const int n    = lane & 15;
    const int quad = lane >> 4;

    __shared__ short A_lds[80 * AK];     // gd bf16, row-major, k-padded
    __shared__ short B_lds[80 * AK];     // WcT bf16: [col n][k]
    __shared__ float desc_lds[FG];
    __shared__ float red[4 * G];

    // stage A: 1600 float4 chunks
    #pragma unroll
    for (int i = 0; i < 5; ++i) {
        int c   = tid + i * 320;         // 0..1599
        int row = c / 20;
        int g4  = (c % 20) * 4;
        float4 v = *(const float4*)&gd[(row * S + s) * G + g4];
        *(ushort4*)&A_lds[row * AK + g4] =
            make_ushort4((unsigned short)bfr(v.x), (unsigned short)bfr(v.y),
                         (unsigned short)bfr(v.z), (unsigned short)bfr(v.w));
    }
    // stage B transposed: Wc[k][n] -> B_lds[n*AK + k]
    #pragma unroll
    for (int i = 0; i < 5; ++i) {
        int c  = tid + i * 320;          // float4 chunk over Wc
        int k  = c / 20;
        int n4 = (c % 20) * 4;
        float4 v = *(const float4*)&Wc[k * G + n4];
        B_lds[(n4 + 0) * AK + k] = bfr(v.x);
        B_lds[(n4 + 1) * AK + k] = bfr(v.y);
        B_lds[(n4 + 2) * AK + k] = bfr(v.z);
        B_lds[(n4 + 3) * AK + k] = bfr(v.w);
    }
    // zero k-pad 80..95
    {
        int row = tid >> 2, seg = tid & 3;
        if (row < 80) {
            *(ushort4*)&A_lds[row * AK + 80 + seg * 4] = make_ushort4(0, 0, 0, 0);
            *(ushort4*)&B_lds[row * AK + 80 + seg * 4] = make_ushort4(0, 0, 0, 0);
        }
    }
    __syncthreads();

    // MFMA: wave w computes rows w*16..w*16+15 (= f=w, r=0..15) x 80 cols
    facc4 acc[5];
    #pragma unroll
    for (int t = 0; t < 5; ++t) acc[t] = (facc4){0.f, 0.f, 0.f, 0.f};

    #pragma unroll
    for (int kk = 0; kk < 3; ++kk) {
        const int ko = kk * 32 + quad * 8;
        bfrag8 af = *(const bfrag8*)&A_lds[(w * 16 + n) * AK + ko];
        #pragma unroll
        for (int t = 0; t < 5; ++t) {
            bfrag8 bf = *(const bfrag8*)&B_lds[(t * 16 + n) * AK + ko];
            acc[t] = __builtin_amdgcn_mfma_f32_16x16x32_bf16(af, bf, acc[t], 0, 0, 0);
        }
    }

    // max over r (rows): in-lane over 4 regs, then across quads; +bias, relu
    #pragma unroll
    for (int t = 0; t < 5; ++t) {
        float m = fmaxf(fmaxf(acc[t][0], acc[t][1]), fmaxf(acc[t][2], acc[t][3]));
        m = fmaxf(m, __shfl_xor(m, 16));
        m = fmaxf(m, __shfl_xor(m, 32));
        if (lane < 16) {
            int gout = t * 16 + n;
            desc_lds[w * G + gout] = fmaxf(m + bc[w * G + gout], 0.f);
        }
    }
    __syncthreads();

    // fused fcc: out[s,:] = desc_row(400) @ fw(400x80) + fb
    {
        const int part = tid / 80;       // 0..3
        const int gout = tid % 80;
        float acc3 = 0.f;
        const int k0 = part * 100;
        #pragma unroll 10
        for (int i = 0; i < 100; ++i) {
            int k = k0 + i;
            acc3 = fmaf(desc_lds[k], fw[k * G + gout], acc3);
        }
        red[part * G + gout] = acc3;
    }
    __syncthreads();
    if (tid < G) {
        out[s * G + tid] = red[tid] + red[G + tid] + red[2 * G + tid]
                         + red[3 * G + tid] + fb[tid];
    }
}

// ---------------- K4: score + data_loss -------------------------------------
__global__ __launch_bounds__(128) void k4_loss(
    const float* __restrict__ gdesc,  // d_out[0 .. S*G)
    float* __restrict__ out)
{
    const int tid  = threadIdx.x;
    const int wave = tid >> 6;
    const int lane = tid & 63;

    const float* a;
    const float* b;
    if (wave == 0) { a = gdesc + (64  + lane) * G; b = gdesc + lane         * G; }
    else           { a = gdesc + (128 + lane) * G; b = gdesc + (192 + lane) * G; }

    float d = 0.f;
    #pragma unroll 8
    for (int g = 0; g < G; ++g) { float df = a[g] - b[g]; d = fmaf(df, df, d); }
    out[OUT_SCORE + tid] = d;

    float rv = (wave == 0) ? fmaxf(d - 0.0f, 0.f) : fmaxf(10.0f - d, 0.f);

    float sum = rv;
    for (int off = 32; off > 0; off >>= 1) sum += __shfl_xor(sum, off);
    float mean = sum * (1.f / 64.f);
    float dv = rv - mean;
    float sq = dv * dv;
    for (int off = 32; off > 0; off >>= 1) sq += __shfl_xor(sq, off);
    float stdv = sqrtf(sq * (1.f / 63.f));   // ddof=1

    __shared__ float part[2];
    if (lane == 0) part[wave] = mean + stdv;
    __syncthreads();
    if (tid == 0) out[OUT_LOSS] = part[0] + part[1];
}

extern "C" void kernel_launch(void* const* d_in, const int* in_sizes, int n_in,
                              void* d_out, int out_size, void* d_ws, size_t ws_size,
                              hipStream_t stream) {
    const float* feat    = (const float*)d_in[0];
    const float* rho     = (const float*)d_in[1];
    const float* theta   = (const float*)d_in[2];
    const float* mask    = (const float*)d_in[3];
    const float* mu_rho  = (const float*)d_in[4];
    const float* sig_rho = (const float*)d_in[5];
    const float* mu_th   = (const float*)d_in[6];
    const float* sig_th  = (const float*)d_in[7];
    const float* Wc      = (const float*)d_in[8];
    const float* bc      = (const float*)d_in[9];
    const float* fw      = (const float*)d_in[10];
    const float* fb      = (const float*)d_in[11];

    float* out = (float*)d_out;
    float* gd  = (float*)d_ws;                 // NF*NROT*S*G floats

    k1_gd      <<<dim3(S, NROT), 64, 0, stream>>>(feat, rho, theta, mask,
                                                  mu_rho, sig_rho, mu_th, sig_th, gd);
    k2_conv_fcc<<<S,            320, 0, stream>>>(gd, Wc, bc, fw, fb, out);
    k4_loss    <<<1,            128, 0, stream>>>(out, out);
}

// Round 4
// 97.940 us; speedup vs baseline: 2.5113x; 1.0879x over previous
//
#include <hip/hip_runtime.h>
#include <math.h>

#define S 256
#define V 200
#define NF 5
#define NROT 16
#define G 80
#define FG 400
#define EPSF 1e-5f
#define T2PI 6.28318530717958647692f
#define NLOG2E (-1.44269504088896340736f)
#define KP 224          // V padded to 7*32 MFMA k-steps
#define VP 228          // FtL row stride (bank-spread, 16B aligned)
#define AK 96           // K=80 padded to 96 for conv MFMA
#define CTP 17          // cT row stride (pad: breaks 16-stride bank conflicts)
#define OUT_LOSS 20480
#define OUT_SCORE 20481

typedef __attribute__((ext_vector_type(8))) short bfrag8;   // 8 bf16 (4 VGPRs)
typedef __attribute__((ext_vector_type(4))) float facc4;    // 4 f32 acc

static __device__ __forceinline__ short bft(float x) {
    return (short)(__float_as_uint(x) >> 16);   // f32 -> bf16 truncate
}
static __device__ __forceinline__ short bfr(float x) {      // round-to-nearest-even
    unsigned u = __float_as_uint(x);
    u += 0x7FFFu + ((u >> 16) & 1u);
    return (short)(u >> 16);
}

// ============ Fused: gaussians -> gd -> conv+max+relu -> fcc, one block/s ====
// 8 waves. k1 phase: wave w handles r = {2w, 2w+1}; B fragments (rho-gauss *
// feat, r-independent) built ONCE per wave in registers; only the theta-gauss
// A fragment is rebuilt per r. gd lands in LDS (bf16, conv-A layout) — never
// global. k2 phase: waves 0-4 do the 80x80 conv MFMA + max_r + relu; then fcc.
__global__ __launch_bounds__(512) void k_fused(
    const float* __restrict__ feat,   // (S,V,NF)
    const float* __restrict__ rho,    // (S,V)
    const float* __restrict__ theta,  // (S,V)
    const float* __restrict__ mask,   // (S,V)
    const float* __restrict__ mu_rho, const float* __restrict__ sig_rho,
    const float* __restrict__ mu_th,  const float* __restrict__ sig_th,
    const float* __restrict__ Wc,     // (G,G)
    const float* __restrict__ bc,     // (NF,G)
    const float* __restrict__ fw,     // (FG,G)
    const float* __restrict__ fb,     // (G)
    float* __restrict__ out)          // d_out: first S*G floats
{
    const int s    = blockIdx.x;
    const int tid  = threadIdx.x;
    const int w    = __builtin_amdgcn_readfirstlane(tid >> 6);  // wave id 0..7
    const int lane = tid & 63;
    const int n    = lane & 15;
    const int quad = lane >> 4;

    __shared__ float thr[KP];            // raw theta (wrap applied per r)
    __shared__ float rhm[KP];
    __shared__ float FtL[6 * VP];        // [fh][v]: feat*mask 0..4, mask row 5
    __shared__ short A_lds[80 * AK];     // gd bf16, rows (f*16+r), k=g
    __shared__ short B_lds[80 * AK];     // WcT bf16: [col][k]
    __shared__ float cT[8 * 32 * CTP];   // per-wave C-transpose slabs
    __shared__ float desc_lds[FG];
    __shared__ float red[5 * G];

    // ---- stage inputs ----
    if (tid < KP) {
        float th = 0.f, rh = 0.f, mk = 0.f;
        float f0 = 0.f, f1 = 0.f, f2 = 0.f, f3 = 0.f, f4 = 0.f;
        if (tid < V) {
            th = theta[s * V + tid];
            rh = rho[s * V + tid];
            mk = mask[s * V + tid];
            const float* fp = &feat[(s * V + tid) * NF];
            f0 = fp[0] * mk; f1 = fp[1] * mk; f2 = fp[2] * mk;
            f3 = fp[3] * mk; f4 = fp[4] * mk;
        }
        thr[tid] = th; rhm[tid] = rh;
        FtL[0 * VP + tid] = f0; FtL[1 * VP + tid] = f1; FtL[2 * VP + tid] = f2;
        FtL[3 * VP + tid] = f3; FtL[4 * VP + tid] = f4; FtL[5 * VP + tid] = mk;
    }
    // stage W_conv transposed -> bf16
    for (int c = tid; c < 1600; c += 512) {
        int k  = c / 20;
        int n4 = (c % 20) * 4;
        float4 v = *(const float4*)&Wc[k * G + n4];
        B_lds[(n4 + 0) * AK + k] = bfr(v.x);
        B_lds[(n4 + 1) * AK + k] = bfr(v.y);
        B_lds[(n4 + 2) * AK + k] = bfr(v.z);
        B_lds[(n4 + 3) * AK + k] = bfr(v.w);
    }
    // zero the k-pad 80..95 of both tiles
    if (tid < 160) {
        int row = tid >> 1, sg = tid & 1;
        uint4 z = {0u, 0u, 0u, 0u};
        *(uint4*)&A_lds[row * AK + 80 + sg * 8] = z;
        *(uint4*)&B_lds[row * AK + 80 + sg * 8] = z;
    }
    __syncthreads();

    // ---- per-lane gaussian constants ----
    const float mu_t = mu_th[n];
    const float stn  = sig_th[n];
    const float cth  = NLOG2E / (stn * stn + EPSF);

    const int   c0 = n;       const int ir0 = c0 / 6, fh0 = c0 % 6;
    const int   c1 = 16 + n;  const bool vl1 = (c1 < 30);
    const int   ir1 = c1 / 6;
    const int   fh1s = vl1 ? (c1 % 6) : 0;
    const float mu_r0 = mu_rho[ir0 * 16];
    const float sr0   = sig_rho[ir0 * 16];
    const float cr0   = NLOG2E / (sr0 * sr0 + EPSF);
    const float mu_r1 = mu_rho[ir1 * 16];
    const float sr1   = sig_rho[ir1 * 16];
    const float cr1   = NLOG2E / (sr1 * sr1 + EPSF);

    // ---- B fragments: rho-gaussian * feat, r-independent, built once ----
    bfrag8 B0[7], B1[7];
    #pragma unroll
    for (int kk = 0; kk < 7; ++kk) {
        const int vb = kk * 32 + quad * 8;
        const float4 p0 = *(const float4*)&rhm[vb];
        const float4 p1 = *(const float4*)&rhm[vb + 4];
        const float4 g0 = *(const float4*)&FtL[fh0 * VP + vb];
        const float4 g1 = *(const float4*)&FtL[fh0 * VP + vb + 4];
        const float4 h0 = *(const float4*)&FtL[fh1s * VP + vb];
        const float4 h1 = *(const float4*)&FtL[fh1s * VP + vb + 4];
        const float pv[8] = {p0.x, p0.y, p0.z, p0.w, p1.x, p1.y, p1.z, p1.w};
        const float gv[8] = {g0.x, g0.y, g0.z, g0.w, g1.x, g1.y, g1.z, g1.w};
        const float hv[8] = {h0.x, h0.y, h0.z, h0.w, h1.x, h1.y, h1.z, h1.w};
        bfrag8 b0, b1;
        #pragma unroll
        for (int j = 0; j < 8; ++j) {
            float dra = pv[j] - mu_r0;
            b0[j] = bft(__builtin_amdgcn_exp2f(cr0 * dra * dra) * gv[j]);
            float drb = pv[j] - mu_r1;
            float w1  = vl1 ? __builtin_amdgcn_exp2f(cr1 * drb * drb) * hv[j] : 0.f;
            b1[j] = bft(w1);
        }
        B0[kk] = b0; B1[kk] = b1;
    }

    // ---- per-r: theta-gaussian A fragment + MFMA + epilogue into A_lds ----
    float* ctw = &cT[w * 32 * CTP];
    for (int rr = 0; rr < 2; ++rr) {
        const int   r   = w * 2 + rr;
        const float rot = (float)r * (float)(6.283185307179586 / 16.0);

        facc4 acc0 = {0.f, 0.f, 0.f, 0.f};
        facc4 acc1 = {0.f, 0.f, 0.f, 0.f};
        #pragma unroll
        for (int kk = 0; kk < 7; ++kk) {
            const int vb = kk * 32 + quad * 8;
            const float4 t0 = *(const float4*)&thr[vb];
            const float4 t1 = *(const float4*)&thr[vb + 4];
            const float tv[8] = {t0.x, t0.y, t0.z, t0.w, t1.x, t1.y, t1.z, t1.w};
            bfrag8 af;
            #pragma unroll
            for (int j = 0; j < 8; ++j) {
                float u = tv[j] + rot;
                u -= (u >= T2PI) ? T2PI : 0.f;     // == jnp.mod(theta+rot, 2pi)
                float dt = u - mu_t;
                af[j] = bft(__builtin_amdgcn_exp2f(cth * dt * dt));
            }
            acc0 = __builtin_amdgcn_mfma_f32_16x16x32_bf16(af, B0[kk], acc0, 0, 0, 0);
            acc1 = __builtin_amdgcn_mfma_f32_16x16x32_bf16(af, B1[kk], acc1, 0, 0, 0);
        }

        // C/D: col=lane&15, row=quad*4+reg -> wave-private transpose slab
        #pragma unroll
        for (int i = 0; i < 4; ++i) {
            ctw[c0 * CTP + quad * 4 + i] = acc0[i];
            ctw[c1 * CTP + quad * 4 + i] = acc1[i];
        }
        // wave-private LDS: in-wave ordering via lgkmcnt, no barrier needed
        for (int i = lane; i < 400; i += 64) {
            int it  = i & 15;
            int c25 = i >> 4;                  // 0..24
            int ir  = c25 / 5, f = c25 - ir * 5;
            float num = ctw[(ir * 6 + f) * CTP + it];
            float den = ctw[(ir * 6 + 5) * CTP + it];
            float q   = num * __builtin_amdgcn_rcpf(den + EPSF);
            A_lds[(f * 16 + r) * AK + ir * 16 + it] = bfr(q);
        }
    }
    __syncthreads();

    // ---- conv MFMA: waves 0..4 (w = f), rows w*16..w*16+15, cols 80 ----
    if (w < 5) {
        facc4 a2[5];
        #pragma unroll
        for (int t = 0; t < 5; ++t) a2[t] = (facc4){0.f, 0.f, 0.f, 0.f};
        #pragma unroll
        for (int kk = 0; kk < 3; ++kk) {
            const int ko = kk * 32 + quad * 8;
            bfrag8 af2 = *(const bfrag8*)&A_lds[(w * 16 + n) * AK + ko];
            #pragma unroll
            for (int t = 0; t < 5; ++t) {
                bfrag8 bf = *(const bfrag8*)&B_lds[(t * 16 + n) * AK + ko];
                a2[t] = __builtin_amdgcn_mfma_f32_16x16x32_bf16(af2, bf, a2[t], 0, 0, 0);
            }
        }
        #pragma unroll
        for (int t = 0; t < 5; ++t) {
            float m = fmaxf(fmaxf(a2[t][0], a2[t][1]), fmaxf(a2[t][2], a2[t][3]));
            m = fmaxf(m, __shfl_xor(m, 16));
            m = fmaxf(m, __shfl_xor(m, 32));
            if (lane < 16) {
                int gout = t * 16 + n;
                desc_lds[w * G + gout] = fmaxf(m + bc[w * G + gout], 0.f);
            }
        }
    }
    __syncthreads();

    // ---- fcc: out[s,:] = desc(400) @ fw(400x80) + fb ----
    if (tid < 400) {
        const int part = tid / 80;       // 0..4
        const int gout = tid - part * 80;
        const int k0   = part * 80;
        float a3 = 0.f;
        #pragma unroll 8
        for (int i = 0; i < 80; ++i) {
            int k = k0 + i;
            a3 = fmaf(desc_lds[k], fw[k * G + gout], a3);
        }
        red[part * G + gout] = a3;
    }
    __syncthreads();
    if (tid < G) {
        out[s * G + tid] = red[tid] + red[G + tid] + red[2 * G + tid]
                         + red[3 * G + tid] + red[4 * G + tid] + fb[tid];
    }
}

// ---------------- K4: score + data_loss -------------------------------------
__global__ __launch_bounds__(128) void k4_loss(
    const float* __restrict__ gdesc,  // d_out[0 .. S*G)
    float* __restrict__ out)
{
    const int tid  = threadIdx.x;
    const int wave = tid >> 6;
    const int lane = tid & 63;

    const float* a;
    const float* b;
    if (wave == 0) { a = gdesc + (64  + lane) * G; b = gdesc + lane         * G; }
    else           { a = gdesc + (128 + lane) * G; b = gdesc + (192 + lane) * G; }

    float d = 0.f;
    #pragma unroll 8
    for (int g = 0; g < G; ++g) { float df = a[g] - b[g]; d = fmaf(df, df, d); }
    out[OUT_SCORE + tid] = d;

    float rv = (wave == 0) ? fmaxf(d - 0.0f, 0.f) : fmaxf(10.0f - d, 0.f);

    float sum = rv;
    for (int off = 32; off > 0; off >>= 1) sum += __shfl_xor(sum, off);
    float mean = sum * (1.f / 64.f);
    float dv = rv - mean;
    float sq = dv * dv;
    for (int off = 32; off > 0; off >>= 1) sq += __shfl_xor(sq, off);
    float stdv = sqrtf(sq * (1.f / 63.f));   // ddof=1

    __shared__ float part[2];
    if (lane == 0) part[wave] = mean + stdv;
    __syncthreads();
    if (tid == 0) out[OUT_LOSS] = part[0] + part[1];
}

extern "C" void kernel_launch(void* const* d_in, const int* in_sizes, int n_in,
                              void* d_out, int out_size, void* d_ws, size_t ws_size,
                              hipStream_t stream) {
    const float* feat    = (const float*)d_in[0];
    const float* rho     = (const float*)d_in[1];
    const float* theta   = (const float*)d_in[2];
    const float* mask    = (const float*)d_in[3];
    const float* mu_rho  = (const float*)d_in[4];
    const float* sig_rho = (const float*)d_in[5];
    const float* mu_th   = (const float*)d_in[6];
    const float* sig_th  = (const float*)d_in[7];
    const float* Wc      = (const float*)d_in[8];
    const float* bc      = (const float*)d_in[9];
    const float* fw      = (const float*)d_in[10];
    const float* fb      = (const float*)d_in[11];

    float* out = (float*)d_out;

    k_fused<<<S, 512, 0, stream>>>(feat, rho, theta, mask,
                                   mu_rho, sig_rho, mu_th, sig_th,
                                   Wc, bc, fw, fb, out);
    k4_loss<<<1, 128, 0, stream>>>(out, out);
}